// Round 9
// baseline (146.983 us; speedup 1.0000x reference)
//
#include <hip/hip_runtime.h>
#include <stdint.h>

// ---------------- problem constants ----------------
#define B    8192
#define D    256
#define C    7
#define NTOT 8199          // B + C
#define NPAD 8320          // 65 * 128 (padded rows)
#define NT   65            // 128-row tiles
#define NBLK 2145          // 65*66/2 triangular
#define BETAC 0.005f       // 0.5*(1-GAMMA)
#define L2GAMMA (-0.0144995696951151f)  // log2(0.99)
#define KC   (6.25f + 1.25e-7f)         // score offset
#define EC1  9.016844005555771f         // 6.25 * log2(e)
#define EC0  9.016844185925551f         // (6.25+1.25e-7) * log2(e)
#define KACCB 128                        // kaccnorm blocks (64 rows each)

using f32x4  = __attribute__((ext_vector_type(4))) float;

__device__ __forceinline__ void async16(const void* src, void* dst) {
    __builtin_amdgcn_global_load_lds(
        (const __attribute__((address_space(1))) void*)src,
        (__attribute__((address_space(3))) void*)dst, 16, 0, 0);
}

#define WAITVM(N) asm volatile("s_waitcnt vmcnt(" #N ")" ::: "memory")
#define BARRIER() do { __builtin_amdgcn_s_barrier(); asm volatile("" ::: "memory"); } while(0)

// ---------------- kernel 1: fused scan+weights+normalize->fp8 G + S/CS partials ----------------
__global__ void kaccnorm(const float* __restrict__ feats, const int* __restrict__ labels,
                         float* __restrict__ Spart, float* __restrict__ CSpart,
                         unsigned* __restrict__ G32, int* __restrict__ labs_ext,
                         int* __restrict__ hist, float* __restrict__ lossacc,
                         unsigned* __restrict__ ticket) {
    __shared__ int cnt[256 * 8];
    __shared__ int tot[8];
    __shared__ float wrow[64];
    __shared__ float sacc[4][7][256];   // 28 KB reduction buffer (S then CS)
    int t = threadIdx.x, lane = t & 63, w = t >> 6;
    int bid = blockIdx.x;

    // ---- full-batch label scan (every block redundantly; deterministic) ----
    int lab[32];
    #pragma unroll
    for (int q = 0; q < 8; ++q) {
        int4 v = *(const int4*)(labels + t * 32 + q * 4);
        lab[q * 4 + 0] = v.x; lab[q * 4 + 1] = v.y;
        lab[q * 4 + 2] = v.z; lab[q * 4 + 3] = v.w;
    }
    int myc[8] = {0, 0, 0, 0, 0, 0, 0, 0};
    #pragma unroll
    for (int k = 0; k < 32; ++k) {
        #pragma unroll
        for (int cc = 0; cc < 7; ++cc) myc[cc] += (lab[k] == cc) ? 1 : 0;
    }
    #pragma unroll
    for (int cc = 0; cc < 8; ++cc) cnt[t * 8 + cc] = myc[cc];
    __syncthreads();
    for (int c = w; c < C; c += 4) {
        int v[4], partial = 0;
        #pragma unroll
        for (int k = 0; k < 4; ++k) { v[k] = cnt[(lane * 4 + k) * 8 + c]; partial += v[k]; }
        int inc = partial;
        #pragma unroll
        for (int d = 1; d < 64; d <<= 1) {
            int y = __shfl_up(inc, d);
            if (lane >= d) inc += y;
        }
        int run = inc - partial;
        #pragma unroll
        for (int k = 0; k < 4; ++k) { int tmp = v[k]; cnt[(lane * 4 + k) * 8 + c] = run; run += tmp; }
        if (lane == 63) { tot[c] = inc; if (bid == 0) hist[c] = inc; }
    }
    __syncthreads();
    // ---- weights for this block's 64 rows (chunks 2bid, 2bid+1) ----
    if (t < 2) {
        int ch = 2 * bid + t;
        int loc[7];
        #pragma unroll
        for (int cc = 0; cc < 7; ++cc) loc[cc] = cnt[ch * 8 + cc];
        for (int k = 0; k < 32; ++k) {
            int c2 = labels[ch * 32 + k];
            int r = ++loc[c2];
            wrow[t * 32 + k] = exp2f((float)(tot[c2] - r) * L2GAMMA);
        }
    }
    if (t < 64) labs_ext[bid * 64 + t] = labels[bid * 64 + t];
    if (bid == 0) {
        if (t == 0) { lossacc[0] = 0.f; lossacc[1] = 0.f; *ticket = 0u; }
        if (t < 128) { int i2 = B + t; labs_ext[i2] = (i2 < NTOT) ? (i2 - B) : -1; }
        // zero fp8 pad rows 8199..8319 (121 rows * 64 uints)
        for (int idx = t; idx < 121 * 64; idx += 256) G32[NTOT * 64 + idx] = 0u;
    }
    __syncthreads();

    // ---- main: normalize -> fp8, accumulate S (w*f) and CS (normalized g) ----
    float acc7[7][4] = {};
    float cs7[7][4] = {};
    int base = bid * 64 + w * 16;
    for (int k = 0; k < 16; ++k) {
        int row = base + k;
        const float4 v = *(const float4*)(feats + (size_t)row * 256 + lane * 4);
        float ss = v.x * v.x + v.y * v.y + v.z * v.z + v.w * v.w;
        #pragma unroll
        for (int off = 1; off < 64; off <<= 1) ss += __shfl_xor(ss, off);
        float rn = 1.f / sqrtf(ss);
        float g0 = v.x * rn, g1 = v.y * rn, g2 = v.z * rn, g3 = v.w * rn;
        unsigned p = (unsigned)__builtin_amdgcn_cvt_pk_fp8_f32(g0, g1, 0, false);
        p = (unsigned)__builtin_amdgcn_cvt_pk_fp8_f32(g2, g3, (int)p, true);
        G32[(size_t)row * 64 + lane] = p;
        int c = labels[row];               // wave-uniform
        float wgt = wrow[w * 16 + k];
        #pragma unroll
        for (int cc = 0; cc < 7; ++cc)
            if (c == cc) {
                acc7[cc][0] += wgt * v.x; acc7[cc][1] += wgt * v.y;
                acc7[cc][2] += wgt * v.z; acc7[cc][3] += wgt * v.w;
                cs7[cc][0] += g0; cs7[cc][1] += g1;
                cs7[cc][2] += g2; cs7[cc][3] += g3;
            }
    }
    #pragma unroll
    for (int cc = 0; cc < 7; ++cc)
        #pragma unroll
        for (int jj = 0; jj < 4; ++jj) sacc[w][cc][lane * 4 + jj] = acc7[cc][jj];
    __syncthreads();
    #pragma unroll
    for (int cc = 0; cc < 7; ++cc)
        Spart[(size_t)bid * 1792 + cc * 256 + t] =
            sacc[0][cc][t] + sacc[1][cc][t] + sacc[2][cc][t] + sacc[3][cc][t];
    __syncthreads();
    #pragma unroll
    for (int cc = 0; cc < 7; ++cc)
        #pragma unroll
        for (int jj = 0; jj < 4; ++jj) sacc[w][cc][lane * 4 + jj] = cs7[cc][jj];
    __syncthreads();
    #pragma unroll
    for (int cc = 0; cc < 7; ++cc)
        CSpart[(size_t)bid * 1792 + cc * 256 + t] =
            sacc[0][cc][t] + sacc[1][cc][t] + sacc[2][cc][t] + sacc[3][cc][t];
}

// ---------------- kernel 2: partial sums + target + Householder QR + proto rows + CSfin ----------------
__global__ void kproto(const float* __restrict__ Spart, const float* __restrict__ CSpart,
                       const int* __restrict__ hist, const float* __restrict__ protos,
                       const float* __restrict__ moms, unsigned char* __restrict__ G8,
                       float* __restrict__ CSfin, float* __restrict__ Pnorm) {
    __shared__ float A[256 * 8];
    __shared__ float V[256 * 8];
    __shared__ float vvs[8];
    __shared__ float bcast[8];
    int t = threadIdx.x;
    int lane = t & 63, w = t >> 6;
    // sum the per-block partials
    float ssum[7] = {}, cssum[7] = {};
    for (int b2 = 0; b2 < KACCB; ++b2) {
        #pragma unroll
        for (int cc = 0; cc < 7; ++cc) {
            ssum[cc]  += Spart[(size_t)b2 * 1792 + cc * 256 + t];
            cssum[cc] += CSpart[(size_t)b2 * 1792 + cc * 256 + t];
        }
    }
    #pragma unroll
    for (int c = 0; c < C; ++c) {
        float p = protos[c * 256 + t];
        float m0 = moms[c * 256 + t];
        float gn = exp2f((float)hist[c] * L2GAMMA);     // gamma^{n_c}
        float mf = gn * m0 + BETAC * ssum[c] - 0.5f * (1.f - gn) * p;
        A[t * 8 + c] = p + mf;
        V[t * 8 + c] = 0.f;
    }
    __syncthreads();
    for (int j = 0; j < C; ++j) {
        if (w == 0) {
            float s = 0.f;
            for (int i = lane; i < 256; i += 64) {
                float a = (i >= j) ? A[i * 8 + j] : 0.f;
                s += a * a;
            }
            #pragma unroll
            for (int off = 32; off; off >>= 1) s += __shfl_xor(s, off);
            if (lane == 0) {
                float norm = sqrtf(s);
                float alpha = A[j * 8 + j];
                float beta = (alpha >= 0.f) ? -norm : norm;
                float vv = 2.f * beta * (beta - alpha);
                bcast[0] = alpha; bcast[1] = beta;
                bcast[2] = (vv > 0.f) ? 1.f : 0.f;
                vvs[j] = (vv > 0.f) ? vv : 1.f;
            }
        }
        __syncthreads();
        float alpha = bcast[0], valid = bcast[2];
        float beta = bcast[1];
        float vi = 0.f;
        if (valid != 0.f) {
            if (t == j) vi = alpha - beta;
            else if (t > j) vi = A[t * 8 + j];
        }
        V[t * 8 + j] = vi;
        __syncthreads();
        float vvj = vvs[j];
        for (int k = j + 1 + w; k < C; k += 4) {
            float cp = 0.f;
            for (int i = lane; i < 256; i += 64) cp += V[i * 8 + j] * A[i * 8 + k];
            #pragma unroll
            for (int off = 32; off; off >>= 1) cp += __shfl_xor(cp, off);
            float scale = 2.f * cp / vvj;
            for (int i = lane; i < 256; i += 64) A[i * 8 + k] -= scale * V[i * 8 + j];
        }
        __syncthreads();
    }
    #pragma unroll
    for (int c = 0; c < C; ++c) A[t * 8 + c] = (t == c) ? 1.f : 0.f;
    __syncthreads();
    for (int j = C - 1; j >= 0; --j) {
        float vvj = vvs[j];
        for (int k = w; k < C; k += 4) {
            float cp = 0.f;
            for (int i = lane; i < 256; i += 64) cp += V[i * 8 + j] * A[i * 8 + k];
            #pragma unroll
            for (int off = 32; off; off >>= 1) cp += __shfl_xor(cp, off);
            float scale = 2.f * cp / vvj;
            for (int i = lane; i < 256; i += 64) A[i * 8 + k] -= scale * V[i * 8 + j];
        }
        __syncthreads();
    }
    for (int c = w; c < C; c += 4) {
        float s = 0.f;
        for (int i = lane; i < 256; i += 64) { float a = A[i * 8 + c]; s += a * a; }
        #pragma unroll
        for (int off = 32; off; off >>= 1) s += __shfl_xor(s, off);
        if (lane == 0) bcast[c] = 1.f / sqrtf(s);
    }
    __syncthreads();
    #pragma unroll
    for (int c = 0; c < C; ++c) {
        float val = A[t * 8 + c] * bcast[c];
        int pk = __builtin_amdgcn_cvt_pk_fp8_f32(val, 0.f, 0, false);
        G8[(size_t)(B + c) * 256 + t] = (unsigned char)(pk & 0xff);
        Pnorm[c * 256 + t] = val;
        CSfin[c * 256 + t] = cssum[c] + val;   // class sums incl. prototype row
    }
}

// ---------------- kernel 3: 128x128 symmetric fused G G^T, neg-only epilogue ----------------
__global__ __launch_bounds__(512, 2) void kmain(const unsigned char* __restrict__ G,
                                                const int* __restrict__ labs,
                                                float* __restrict__ pN) {
    __shared__ unsigned char Asm_[128 * 256];   // full-K fp8 A tile (32 KB)
    __shared__ unsigned char Bsm_[128 * 256];   // full-K fp8 B tile (32 KB)
    // epilogue overlays into Asm_ (after a barrier): 6 x [128] floats
    float* rowN = (float*)Asm_;                 // [2][128]
    float* colN = rowN + 256;                   // [4][128]

    // bijective XCD swizzle: NBLK = 2145 = 8*268 + 1 (residue 0 gets 269)
    int b0 = blockIdx.x;
    int xcd = b0 & 7, pos = b0 >> 3;
    int b = (xcd == 0) ? pos : (269 + (xcd - 1) * 268 + pos);

    // triangular decode: pairs (it <= jt)
    int jt = (int)((sqrtf(8.f * (float)b + 1.f) - 1.f) * 0.5f);
    while ((jt * (jt + 1)) / 2 > b) --jt;
    while (((jt + 1) * (jt + 2)) / 2 <= b) ++jt;
    int it = b - (jt * (jt + 1)) / 2;

    int rowA = it * 128, rowB = jt * 128;
    int tid = threadIdx.x, lane = tid & 63, w8 = tid >> 6;
    int wr = w8 >> 1, wc = w8 & 1;              // 4x2 wave grid: 32 rows x 64 cols per wave
    int g4 = lane >> 4, q15 = lane & 15;

    const char* gb = (const char*)G;

    // ---- single-shot staging: 8 loads/thread in flight, one wait.
    #pragma unroll
    for (int q = 0; q < 4; ++q) {
        int o = q * 8192 + tid * 16;
        int row = o >> 8, colb = o & 255;
        int sc = colb ^ ((row & 15) << 4);
        async16(gb + (size_t)(rowA + row) * 256 + sc, (char*)Asm_ + o);
    }
    #pragma unroll
    for (int q = 0; q < 4; ++q) {
        int o = q * 8192 + tid * 16;
        int row = o >> 8, colb = o & 255;
        int sc = colb ^ ((row & 15) << 4);
        async16(gb + (size_t)(rowB + row) * 256 + sc, (char*)Bsm_ + o);
    }

    // label prefetch into registers — overlaps the stage latency
    int ljv[4];
    #pragma unroll
    for (int n = 0; n < 4; ++n) ljv[n] = labs[rowB + wc * 64 + n * 16 + q15];
    int4 lrow[2];
    #pragma unroll
    for (int m = 0; m < 2; ++m)
        lrow[m] = *(const int4*)(labs + rowA + wr * 32 + m * 16 + g4 * 4);

    f32x4 acc[2][4];
    #pragma unroll
    for (int m = 0; m < 2; ++m)
        #pragma unroll
        for (int n = 0; n < 4; ++n) acc[m][n] = 0.f;

    WAITVM(0);
    BARRIER();

    // ---- mega K-step: 64 MFMA per wave, no barriers
    #pragma unroll
    for (int kk = 0; kk < 8; ++kk) {
        long af[2], bfr[4];
        int cb = (kk * 32 + g4 * 8) ^ (q15 << 4);
        #pragma unroll
        for (int m = 0; m < 2; ++m) {
            int r0 = wr * 32 + m * 16 + q15;
            af[m] = *(const long*)((const char*)Asm_ + r0 * 256 + cb);
        }
        #pragma unroll
        for (int n = 0; n < 4; ++n) {
            int r0 = wc * 64 + n * 16 + q15;
            bfr[n] = *(const long*)((const char*)Bsm_ + r0 * 256 + cb);
        }
        __builtin_amdgcn_s_setprio(1);
        #pragma unroll
        for (int m = 0; m < 2; ++m)
            #pragma unroll
            for (int n = 0; n < 4; ++n)
                acc[m][n] = __builtin_amdgcn_mfma_f32_16x16x32_fp8_fp8(af[m], bfr[n], acc[m][n], 0, 0, 0);
        __builtin_amdgcn_s_setprio(0);
    }

    __syncthreads();   // all LDS reads done before epilogue overlay writes

    // ---- neg-only epilogue: e = exp(score) = exp2(fma(sim, EC1, EC0))
    float cn[4] = {0.f, 0.f, 0.f, 0.f};
    bool fastpath = (it != jt) && (jt != NT - 1);

#define EPI(VALIDEXPR)                                                         \
    _Pragma("unroll")                                                          \
    for (int m = 0; m < 2; ++m) {                                              \
        _Pragma("unroll")                                                      \
        for (int r = 0; r < 4; ++r) {                                          \
            int il = wr * 32 + m * 16 + g4 * 4 + r;                            \
            int i = rowA + il; (void)i;                                        \
            int li = ((const int*)&lrow[m])[r];                                \
            float ns = 0.f;                                                    \
            _Pragma("unroll")                                                  \
            for (int n = 0; n < 4; ++n) {                                      \
                int j = rowB + wc * 64 + n * 16 + q15; (void)j;                \
                float sim = acc[m][n][r];                                      \
                float e = exp2f(fmaf(sim, EC1, EC0));                          \
                bool keep = (VALIDEXPR) && (li != ljv[n]);                     \
                float me = keep ? e : 0.f;                                     \
                ns += me; cn[n] += me;                                         \
            }                                                                  \
            _Pragma("unroll")                                                  \
            for (int off = 1; off < 16; off <<= 1) ns += __shfl_xor(ns, off);  \
            if (q15 == 0) rowN[wc * 128 + il] = ns;                            \
        }                                                                      \
    }

    if (fastpath) { EPI(true); }
    else          { EPI(i < NTOT && j < NTOT && i != j); }
#undef EPI

    // col-side: reduce over g4 groups (same q15-column, different rows)
    #pragma unroll
    for (int n = 0; n < 4; ++n) {
        float a = cn[n];
        a += __shfl_xor(a, 16); a += __shfl_xor(a, 32);
        if (g4 == 0) colN[wr * 128 + wc * 64 + n * 16 + q15] = a;
    }

    __syncthreads();
    if (tid < 128) {
        pN[(size_t)jt * NPAD + rowA + tid] = rowN[tid] + rowN[128 + tid];
    } else if (tid < 256 && it != jt) {
        int tt = tid - 128;
        pN[(size_t)it * NPAD + rowB + tt] = colN[tt] + colN[128 + tt] + colN[256 + tt] + colN[384 + tt];
    }
}

// ---------------- kernel 4: neg reduce + closed-form pos + masked-mean finalize ----------------
__global__ void kreduce(const float* __restrict__ pN, const float* __restrict__ feats,
                        const float* __restrict__ Pnorm, const float* __restrict__ CSfin,
                        const int* __restrict__ hist, const int* __restrict__ labs,
                        float* __restrict__ lossacc, unsigned* __restrict__ ticket,
                        float* __restrict__ out) {
    __shared__ float cls[7 * 264];   // padded class-sum vectors (bank-spread)
    int tid = threadIdx.x;
    for (int idx = tid; idx < 7 * 256; idx += 256)
        cls[(idx >> 8) * 264 + (idx & 255)] = CSfin[idx];
    __syncthreads();

    int i = blockIdx.x * 256 + tid;
    float lsum = 0.f, lcnt = 0.f;
    if (i < NTOT) {
        float sn = 0.f;
        #pragma unroll 5
        for (int c = 0; c < NT; ++c) sn += pN[(size_t)c * NPAD + i];

        int c = labs[i];
        const float* cv = cls + c * 264;
        float dot = 0.f;
        if (i < B) {
            float ss = 0.f;
            const float* fr = feats + (size_t)i * 256;
            for (int k4 = 0; k4 < 64; ++k4) {
                float4 v = *(const float4*)(fr + k4 * 4);
                float4 cvv = *(const float4*)(cv + k4 * 4);
                ss += v.x * v.x + v.y * v.y + v.z * v.z + v.w * v.w;
                dot += v.x * cvv.x + v.y * cvv.y + v.z * cvv.z + v.w * cvv.w;
            }
            dot *= 1.f / sqrtf(ss);
        } else {
            const float* pr = Pnorm + (size_t)(i - B) * 256;
            for (int k4 = 0; k4 < 64; ++k4) {
                float4 v = *(const float4*)(pr + k4 * 4);
                float4 cvv = *(const float4*)(cv + k4 * 4);
                dot += v.x * cvv.x + v.y * cvv.y + v.z * cvv.z + v.w * cvv.w;
            }
        }
        float cnt = (float)hist[c];
        // pos = (sum of same-class scores excl. self) / (cnt + eps); M=0 shift
        float pos = (6.25f * (dot - 1.f) + cnt * KC) / (cnt + 1e-8f);
        float neg = logf(sn + 1e-8f);
        float loss = neg - pos;
        if (loss > 0.f) { lsum = loss; lcnt = 1.f; }
    }
    #pragma unroll
    for (int off = 1; off < 64; off <<= 1) {
        lsum += __shfl_xor(lsum, off);
        lcnt += __shfl_xor(lcnt, off);
    }
    __shared__ float s1[4], s2[4];
    int lane = tid & 63, w = tid >> 6;
    if (lane == 0) { s1[w] = lsum; s2[w] = lcnt; }
    __syncthreads();
    if (tid == 0) {
        atomicAdd(&lossacc[0], s1[0] + s1[1] + s1[2] + s1[3]);
        atomicAdd(&lossacc[1], s2[0] + s2[1] + s2[2] + s2[3]);
        __threadfence();
        unsigned tk = atomicAdd(ticket, 1u);
        if (tk == 32) {   // last of 33 blocks
            float a = atomicAdd(&lossacc[0], 0.f);
            float c2 = atomicAdd(&lossacc[1], 0.f);
            out[0] = (c2 > 0.f) ? a / fmaxf(c2, 1.f) : 0.f;
        }
    }
}

// ---------------- launcher ----------------
extern "C" void kernel_launch(void* const* d_in, const int* in_sizes, int n_in,
                              void* d_out, int out_size, void* d_ws, size_t ws_size,
                              hipStream_t stream) {
    const float* feats  = (const float*)d_in[0];
    const int*   labels = (const int*)d_in[1];
    const float* protos = (const float*)d_in[2];
    const float* moms   = (const float*)d_in[3];
    float* out = (float*)d_out;

    char* ws = (char*)d_ws;
    int*      hist    = (int*)  (ws + 0);        // 8 int
    float*    lossacc = (float*)(ws + 32);       // 2 f32
    unsigned* ticket  = (unsigned*)(ws + 40);    // 1 u32
    float*    CSfin   = (float*)(ws + 64);       // 1792 f32   -> 7232
    float*    Pnorm   = (float*)(ws + 7232);     // 1792 f32   -> 14400
    int*      labs    = (int*)  (ws + 14400);    // 8320 int   -> 47680
    float*    Spart   = (float*)(ws + 47744);    // 128*1792   -> 965248
    float*    CSpart  = (float*)(ws + 965248);   // 128*1792   -> 1882752
    unsigned char* G  = (unsigned char*)(ws + 1882752);  // 8320*256 fp8 -> 4012672
    float*    pN      = (float*)(ws + 4012672);  // 65*8320 f32 -> 6175872

    kaccnorm<<<KACCB, 256, 0, stream>>>(feats, labels, Spart, CSpart,
                                        (unsigned*)G, labs, hist, lossacc, ticket);
    kproto<<<1, 256, 0, stream>>>(Spart, CSpart, hist, protos, moms, G, CSfin, Pnorm);
    kmain<<<NBLK, 512, 0, stream>>>(G, labs, pN);
    kreduce<<<33, 256, 0, stream>>>(pN, feats, Pnorm, CSfin, hist, labs,
                                    lossacc, ticket, out);
}

// Round 10
// 111.009 us; speedup vs baseline: 1.3241x; 1.3241x over previous
//
#include <hip/hip_runtime.h>
#include <stdint.h>

// ---------------- problem constants ----------------
#define B    8192
#define D    256
#define C    7
#define NTOT 8199          // B + C
#define NPAD 8320          // 65 * 128 (padded rows)
#define NT   65            // 128-row tiles
#define NBLK 2145          // 65*66/2 triangular
#define BETAC 0.005f       // 0.5*(1-GAMMA)
#define L2GAMMA (-0.0144995696951151f)  // log2(0.99)
#define KC   (6.25f + 1.25e-7f)         // score offset
#define EC1  9.016844005555771f         // 6.25 * log2(e)
#define EC0  9.016844185925551f         // (6.25+1.25e-7) * log2(e)
#define KACCB 128                        // kaccnorm blocks (64 rows each)

using f32x4  = __attribute__((ext_vector_type(4))) float;

__device__ __forceinline__ void async16(const void* src, void* dst) {
    __builtin_amdgcn_global_load_lds(
        (const __attribute__((address_space(1))) void*)src,
        (__attribute__((address_space(3))) void*)dst, 16, 0, 0);
}

#define WAITVM(N) asm volatile("s_waitcnt vmcnt(" #N ")" ::: "memory")
#define BARRIER() do { __builtin_amdgcn_s_barrier(); asm volatile("" ::: "memory"); } while(0)

// ---------------- kernel 1: fused scan+weights+normalize->fp8 G + atomic S/CS ----------------
__global__ void kaccnorm(const float* __restrict__ feats, const int* __restrict__ labels,
                         float* __restrict__ S, float* __restrict__ CSacc,
                         unsigned* __restrict__ G32, int* __restrict__ labs_ext,
                         int* __restrict__ hist) {
    __shared__ int cnt[256 * 8];
    __shared__ int tot[8];
    __shared__ float wrow[64];
    __shared__ float sacc[4][7][256];   // 28 KB reduction buffer (S then CS)
    int t = threadIdx.x, lane = t & 63, w = t >> 6;
    int bid = blockIdx.x;

    // ---- full-batch label scan (every block redundantly; deterministic) ----
    int lab[32];
    #pragma unroll
    for (int q = 0; q < 8; ++q) {
        int4 v = *(const int4*)(labels + t * 32 + q * 4);
        lab[q * 4 + 0] = v.x; lab[q * 4 + 1] = v.y;
        lab[q * 4 + 2] = v.z; lab[q * 4 + 3] = v.w;
    }
    int myc[8] = {0, 0, 0, 0, 0, 0, 0, 0};
    #pragma unroll
    for (int k = 0; k < 32; ++k) {
        #pragma unroll
        for (int cc = 0; cc < 7; ++cc) myc[cc] += (lab[k] == cc) ? 1 : 0;
    }
    #pragma unroll
    for (int cc = 0; cc < 8; ++cc) cnt[t * 8 + cc] = myc[cc];
    __syncthreads();
    for (int c = w; c < C; c += 4) {
        int v[4], partial = 0;
        #pragma unroll
        for (int k = 0; k < 4; ++k) { v[k] = cnt[(lane * 4 + k) * 8 + c]; partial += v[k]; }
        int inc = partial;
        #pragma unroll
        for (int d = 1; d < 64; d <<= 1) {
            int y = __shfl_up(inc, d);
            if (lane >= d) inc += y;
        }
        int run = inc - partial;
        #pragma unroll
        for (int k = 0; k < 4; ++k) { int tmp = v[k]; cnt[(lane * 4 + k) * 8 + c] = run; run += tmp; }
        if (lane == 63) { tot[c] = inc; if (bid == 0) hist[c] = inc; }
    }
    __syncthreads();
    // ---- weights for this block's 64 rows (chunks 2bid, 2bid+1) ----
    if (t < 2) {
        int ch = 2 * bid + t;
        int loc[7];
        #pragma unroll
        for (int cc = 0; cc < 7; ++cc) loc[cc] = cnt[ch * 8 + cc];
        for (int k = 0; k < 32; ++k) {
            int c2 = labels[ch * 32 + k];
            int r = ++loc[c2];
            wrow[t * 32 + k] = exp2f((float)(tot[c2] - r) * L2GAMMA);
        }
    }
    if (t < 64) labs_ext[bid * 64 + t] = labels[bid * 64 + t];
    if (bid == 0) {
        if (t < 128) { int i2 = B + t; labs_ext[i2] = (i2 < NTOT) ? (i2 - B) : -1; }
        // zero fp8 pad rows 8199..8319 (121 rows * 64 uints)
        for (int idx = t; idx < 121 * 64; idx += 256) G32[NTOT * 64 + idx] = 0u;
    }
    __syncthreads();

    // ---- main: normalize -> fp8, accumulate S (w*f) and CS (normalized g) ----
    float acc7[7][4] = {};
    float cs7[7][4] = {};
    int base = bid * 64 + w * 16;
    for (int k = 0; k < 16; ++k) {
        int row = base + k;
        const float4 v = *(const float4*)(feats + (size_t)row * 256 + lane * 4);
        float ss = v.x * v.x + v.y * v.y + v.z * v.z + v.w * v.w;
        #pragma unroll
        for (int off = 1; off < 64; off <<= 1) ss += __shfl_xor(ss, off);
        float rn = 1.f / sqrtf(ss);
        float g0 = v.x * rn, g1 = v.y * rn, g2 = v.z * rn, g3 = v.w * rn;
        unsigned p = (unsigned)__builtin_amdgcn_cvt_pk_fp8_f32(g0, g1, 0, false);
        p = (unsigned)__builtin_amdgcn_cvt_pk_fp8_f32(g2, g3, (int)p, true);
        G32[(size_t)row * 64 + lane] = p;
        int c = labels[row];               // wave-uniform
        float wgt = wrow[w * 16 + k];
        #pragma unroll
        for (int cc = 0; cc < 7; ++cc)
            if (c == cc) {
                acc7[cc][0] += wgt * v.x; acc7[cc][1] += wgt * v.y;
                acc7[cc][2] += wgt * v.z; acc7[cc][3] += wgt * v.w;
                cs7[cc][0] += g0; cs7[cc][1] += g1;
                cs7[cc][2] += g2; cs7[cc][3] += g3;
            }
    }
    #pragma unroll
    for (int cc = 0; cc < 7; ++cc)
        #pragma unroll
        for (int jj = 0; jj < 4; ++jj) sacc[w][cc][lane * 4 + jj] = acc7[cc][jj];
    __syncthreads();
    #pragma unroll
    for (int cc = 0; cc < 7; ++cc) {
        float s = sacc[0][cc][t] + sacc[1][cc][t] + sacc[2][cc][t] + sacc[3][cc][t];
        atomicAdd(&S[cc * 256 + t], s);
    }
    __syncthreads();
    #pragma unroll
    for (int cc = 0; cc < 7; ++cc)
        #pragma unroll
        for (int jj = 0; jj < 4; ++jj) sacc[w][cc][lane * 4 + jj] = cs7[cc][jj];
    __syncthreads();
    #pragma unroll
    for (int cc = 0; cc < 7; ++cc) {
        float s = sacc[0][cc][t] + sacc[1][cc][t] + sacc[2][cc][t] + sacc[3][cc][t];
        atomicAdd(&CSacc[cc * 256 + t], s);
    }
}

// ---------------- kernel 2: target + Householder QR + proto rows + CSfin ----------------
__global__ void kproto(const float* __restrict__ S, const float* __restrict__ CSacc,
                       const int* __restrict__ hist, const float* __restrict__ protos,
                       const float* __restrict__ moms, unsigned char* __restrict__ G8,
                       float* __restrict__ CSfin, float* __restrict__ Pnorm) {
    __shared__ float A[256 * 8];
    __shared__ float V[256 * 8];
    __shared__ float vvs[8];
    __shared__ float bcast[8];
    int t = threadIdx.x;
    int lane = t & 63, w = t >> 6;
    float cssum[7];
    #pragma unroll
    for (int cc = 0; cc < 7; ++cc) cssum[cc] = CSacc[cc * 256 + t];
    #pragma unroll
    for (int c = 0; c < C; ++c) {
        float p = protos[c * 256 + t];
        float m0 = moms[c * 256 + t];
        float gn = exp2f((float)hist[c] * L2GAMMA);     // gamma^{n_c}
        float mf = gn * m0 + BETAC * S[c * 256 + t] - 0.5f * (1.f - gn) * p;
        A[t * 8 + c] = p + mf;
        V[t * 8 + c] = 0.f;
    }
    __syncthreads();
    for (int j = 0; j < C; ++j) {
        if (w == 0) {
            float s = 0.f;
            for (int i = lane; i < 256; i += 64) {
                float a = (i >= j) ? A[i * 8 + j] : 0.f;
                s += a * a;
            }
            #pragma unroll
            for (int off = 32; off; off >>= 1) s += __shfl_xor(s, off);
            if (lane == 0) {
                float norm = sqrtf(s);
                float alpha = A[j * 8 + j];
                float beta = (alpha >= 0.f) ? -norm : norm;
                float vv = 2.f * beta * (beta - alpha);
                bcast[0] = alpha; bcast[1] = beta;
                bcast[2] = (vv > 0.f) ? 1.f : 0.f;
                vvs[j] = (vv > 0.f) ? vv : 1.f;
            }
        }
        __syncthreads();
        float alpha = bcast[0], valid = bcast[2];
        float beta = bcast[1];
        float vi = 0.f;
        if (valid != 0.f) {
            if (t == j) vi = alpha - beta;
            else if (t > j) vi = A[t * 8 + j];
        }
        V[t * 8 + j] = vi;
        __syncthreads();
        float vvj = vvs[j];
        for (int k = j + 1 + w; k < C; k += 4) {
            float cp = 0.f;
            for (int i = lane; i < 256; i += 64) cp += V[i * 8 + j] * A[i * 8 + k];
            #pragma unroll
            for (int off = 32; off; off >>= 1) cp += __shfl_xor(cp, off);
            float scale = 2.f * cp / vvj;
            for (int i = lane; i < 256; i += 64) A[i * 8 + k] -= scale * V[i * 8 + j];
        }
        __syncthreads();
    }
    #pragma unroll
    for (int c = 0; c < C; ++c) A[t * 8 + c] = (t == c) ? 1.f : 0.f;
    __syncthreads();
    for (int j = C - 1; j >= 0; --j) {
        float vvj = vvs[j];
        for (int k = w; k < C; k += 4) {
            float cp = 0.f;
            for (int i = lane; i < 256; i += 64) cp += V[i * 8 + j] * A[i * 8 + k];
            #pragma unroll
            for (int off = 32; off; off >>= 1) cp += __shfl_xor(cp, off);
            float scale = 2.f * cp / vvj;
            for (int i = lane; i < 256; i += 64) A[i * 8 + k] -= scale * V[i * 8 + j];
        }
        __syncthreads();
    }
    for (int c = w; c < C; c += 4) {
        float s = 0.f;
        for (int i = lane; i < 256; i += 64) { float a = A[i * 8 + c]; s += a * a; }
        #pragma unroll
        for (int off = 32; off; off >>= 1) s += __shfl_xor(s, off);
        if (lane == 0) bcast[c] = 1.f / sqrtf(s);
    }
    __syncthreads();
    #pragma unroll
    for (int c = 0; c < C; ++c) {
        float val = A[t * 8 + c] * bcast[c];
        int pk = __builtin_amdgcn_cvt_pk_fp8_f32(val, 0.f, 0, false);
        G8[(size_t)(B + c) * 256 + t] = (unsigned char)(pk & 0xff);
        Pnorm[c * 256 + t] = val;
        CSfin[c * 256 + t] = cssum[c] + val;   // class sums incl. prototype row
    }
}

// ---------------- kernel 3: 128x128 symmetric fused G G^T, neg-only epilogue ----------------
__global__ __launch_bounds__(512, 2) void kmain(const unsigned char* __restrict__ G,
                                                const int* __restrict__ labs,
                                                float* __restrict__ pN) {
    __shared__ unsigned char Asm_[128 * 256];   // full-K fp8 A tile (32 KB)
    __shared__ unsigned char Bsm_[128 * 256];   // full-K fp8 B tile (32 KB)
    // epilogue overlays into Asm_ (after a barrier): 6 x [128] floats
    float* rowN = (float*)Asm_;                 // [2][128]
    float* colN = rowN + 256;                   // [4][128]

    // bijective XCD swizzle: NBLK = 2145 = 8*268 + 1 (residue 0 gets 269)
    int b0 = blockIdx.x;
    int xcd = b0 & 7, pos = b0 >> 3;
    int b = (xcd == 0) ? pos : (269 + (xcd - 1) * 268 + pos);

    // triangular decode: pairs (it <= jt)
    int jt = (int)((sqrtf(8.f * (float)b + 1.f) - 1.f) * 0.5f);
    while ((jt * (jt + 1)) / 2 > b) --jt;
    while (((jt + 1) * (jt + 2)) / 2 <= b) ++jt;
    int it = b - (jt * (jt + 1)) / 2;

    int rowA = it * 128, rowB = jt * 128;
    int tid = threadIdx.x, lane = tid & 63, w8 = tid >> 6;
    int wr = w8 >> 1, wc = w8 & 1;              // 4x2 wave grid: 32 rows x 64 cols per wave
    int g4 = lane >> 4, q15 = lane & 15;

    const char* gb = (const char*)G;

    // ---- single-shot staging: 8 loads/thread in flight, one wait.
    #pragma unroll
    for (int q = 0; q < 4; ++q) {
        int o = q * 8192 + tid * 16;
        int row = o >> 8, colb = o & 255;
        int sc = colb ^ ((row & 15) << 4);
        async16(gb + (size_t)(rowA + row) * 256 + sc, (char*)Asm_ + o);
    }
    #pragma unroll
    for (int q = 0; q < 4; ++q) {
        int o = q * 8192 + tid * 16;
        int row = o >> 8, colb = o & 255;
        int sc = colb ^ ((row & 15) << 4);
        async16(gb + (size_t)(rowB + row) * 256 + sc, (char*)Bsm_ + o);
    }

    // label prefetch into registers — overlaps the stage latency
    int ljv[4];
    #pragma unroll
    for (int n = 0; n < 4; ++n) ljv[n] = labs[rowB + wc * 64 + n * 16 + q15];
    int4 lrow[2];
    #pragma unroll
    for (int m = 0; m < 2; ++m)
        lrow[m] = *(const int4*)(labs + rowA + wr * 32 + m * 16 + g4 * 4);

    f32x4 acc[2][4];
    #pragma unroll
    for (int m = 0; m < 2; ++m)
        #pragma unroll
        for (int n = 0; n < 4; ++n) acc[m][n] = 0.f;

    WAITVM(0);
    BARRIER();

    // ---- mega K-step: 64 MFMA per wave, no barriers
    #pragma unroll
    for (int kk = 0; kk < 8; ++kk) {
        long af[2], bfr[4];
        int cb = (kk * 32 + g4 * 8) ^ (q15 << 4);
        #pragma unroll
        for (int m = 0; m < 2; ++m) {
            int r0 = wr * 32 + m * 16 + q15;
            af[m] = *(const long*)((const char*)Asm_ + r0 * 256 + cb);
        }
        #pragma unroll
        for (int n = 0; n < 4; ++n) {
            int r0 = wc * 64 + n * 16 + q15;
            bfr[n] = *(const long*)((const char*)Bsm_ + r0 * 256 + cb);
        }
        __builtin_amdgcn_s_setprio(1);
        #pragma unroll
        for (int m = 0; m < 2; ++m)
            #pragma unroll
            for (int n = 0; n < 4; ++n)
                acc[m][n] = __builtin_amdgcn_mfma_f32_16x16x32_fp8_fp8(af[m], bfr[n], acc[m][n], 0, 0, 0);
        __builtin_amdgcn_s_setprio(0);
    }

    __syncthreads();   // all LDS reads done before epilogue overlay writes

    // ---- neg-only epilogue: e = exp(score) = exp2(fma(sim, EC1, EC0))
    float cn[4] = {0.f, 0.f, 0.f, 0.f};
    bool fastpath = (it != jt) && (jt != NT - 1);

#define EPI(VALIDEXPR)                                                         \
    _Pragma("unroll")                                                          \
    for (int m = 0; m < 2; ++m) {                                              \
        _Pragma("unroll")                                                      \
        for (int r = 0; r < 4; ++r) {                                          \
            int il = wr * 32 + m * 16 + g4 * 4 + r;                            \
            int i = rowA + il; (void)i;                                        \
            int li = ((const int*)&lrow[m])[r];                                \
            float ns = 0.f;                                                    \
            _Pragma("unroll")                                                  \
            for (int n = 0; n < 4; ++n) {                                      \
                int j = rowB + wc * 64 + n * 16 + q15; (void)j;                \
                float sim = acc[m][n][r];                                      \
                float e = exp2f(fmaf(sim, EC1, EC0));                          \
                bool keep = (VALIDEXPR) && (li != ljv[n]);                     \
                float me = keep ? e : 0.f;                                     \
                ns += me; cn[n] += me;                                         \
            }                                                                  \
            _Pragma("unroll")                                                  \
            for (int off = 1; off < 16; off <<= 1) ns += __shfl_xor(ns, off);  \
            if (q15 == 0) rowN[wc * 128 + il] = ns;                            \
        }                                                                      \
    }

    if (fastpath) { EPI(true); }
    else          { EPI(i < NTOT && j < NTOT && i != j); }
#undef EPI

    // col-side: reduce over g4 groups (same q15-column, different rows)
    #pragma unroll
    for (int n = 0; n < 4; ++n) {
        float a = cn[n];
        a += __shfl_xor(a, 16); a += __shfl_xor(a, 32);
        if (g4 == 0) colN[wr * 128 + wc * 64 + n * 16 + q15] = a;
    }

    __syncthreads();
    if (tid < 128) {
        pN[(size_t)jt * NPAD + rowA + tid] = rowN[tid] + rowN[128 + tid];
    } else if (tid < 256 && it != jt) {
        int tt = tid - 128;
        pN[(size_t)it * NPAD + rowB + tt] = colN[tt] + colN[128 + tt] + colN[256 + tt] + colN[384 + tt];
    }
}

// ---------------- kernel 4: neg reduce + closed-form pos + masked-mean finalize ----------------
__global__ void kreduce(const float* __restrict__ pN, const float* __restrict__ feats,
                        const float* __restrict__ Pnorm, const float* __restrict__ CSfin,
                        const int* __restrict__ hist, const int* __restrict__ labs,
                        float* __restrict__ lossacc, unsigned* __restrict__ ticket,
                        float* __restrict__ out) {
    __shared__ float cls[7 * 264];   // padded class-sum vectors (bank-spread)
    int tid = threadIdx.x;
    for (int idx = tid; idx < 7 * 256; idx += 256)
        cls[(idx >> 8) * 264 + (idx & 255)] = CSfin[idx];
    __syncthreads();

    int i = blockIdx.x * 256 + tid;
    float lsum = 0.f, lcnt = 0.f;
    if (i < NTOT) {
        float sn = 0.f;
        #pragma unroll 5
        for (int c = 0; c < NT; ++c) sn += pN[(size_t)c * NPAD + i];

        int c = labs[i];
        const float* cv = cls + c * 264;
        float dot = 0.f;
        if (i < B) {
            float ss = 0.f;
            const float* fr = feats + (size_t)i * 256;
            for (int k4 = 0; k4 < 64; ++k4) {
                float4 v = *(const float4*)(fr + k4 * 4);
                float4 cvv = *(const float4*)(cv + k4 * 4);
                ss += v.x * v.x + v.y * v.y + v.z * v.z + v.w * v.w;
                dot += v.x * cvv.x + v.y * cvv.y + v.z * cvv.z + v.w * cvv.w;
            }
            dot *= 1.f / sqrtf(ss);
        } else {
            const float* pr = Pnorm + (size_t)(i - B) * 256;
            for (int k4 = 0; k4 < 64; ++k4) {
                float4 v = *(const float4*)(pr + k4 * 4);
                float4 cvv = *(const float4*)(cv + k4 * 4);
                dot += v.x * cvv.x + v.y * cvv.y + v.z * cvv.z + v.w * cvv.w;
            }
        }
        float cnt = (float)hist[c];
        // pos = (sum of same-class scores excl. self) / (cnt + eps); M=0 shift
        float pos = (6.25f * (dot - 1.f) + cnt * KC) / (cnt + 1e-8f);
        float neg = logf(sn + 1e-8f);
        float loss = neg - pos;
        if (loss > 0.f) { lsum = loss; lcnt = 1.f; }
    }
    #pragma unroll
    for (int off = 1; off < 64; off <<= 1) {
        lsum += __shfl_xor(lsum, off);
        lcnt += __shfl_xor(lcnt, off);
    }
    __shared__ float s1[4], s2[4];
    int lane = tid & 63, w = tid >> 6;
    if (lane == 0) { s1[w] = lsum; s2[w] = lcnt; }
    __syncthreads();
    if (tid == 0) {
        atomicAdd(&lossacc[0], s1[0] + s1[1] + s1[2] + s1[3]);
        atomicAdd(&lossacc[1], s2[0] + s2[1] + s2[2] + s2[3]);
        __threadfence();
        unsigned tk = atomicAdd(ticket, 1u);
        if (tk == 32) {   // last of 33 blocks
            float a = atomicAdd(&lossacc[0], 0.f);
            float c2 = atomicAdd(&lossacc[1], 0.f);
            out[0] = (c2 > 0.f) ? a / fmaxf(c2, 1.f) : 0.f;
        }
    }
}

// ---------------- launcher ----------------
extern "C" void kernel_launch(void* const* d_in, const int* in_sizes, int n_in,
                              void* d_out, int out_size, void* d_ws, size_t ws_size,
                              hipStream_t stream) {
    const float* feats  = (const float*)d_in[0];
    const int*   labels = (const int*)d_in[1];
    const float* protos = (const float*)d_in[2];
    const float* moms   = (const float*)d_in[3];
    float* out = (float*)d_out;

    char* ws = (char*)d_ws;
    float*    S_      = (float*)(ws + 0);        // 1792 f32  -> 7168
    float*    CSacc   = (float*)(ws + 7168);     // 1792 f32  -> 14336
    int*      hist    = (int*)  (ws + 14336);    // 8 int     -> 14368
    float*    lossacc = (float*)(ws + 14368);    // 2 f32     -> 14376
    unsigned* ticket  = (unsigned*)(ws + 14376); // 1 u32     -> 14380
    float*    CSfin   = (float*)(ws + 14400);    // 1792 f32  -> 21568
    float*    Pnorm   = (float*)(ws + 21568);    // 1792 f32  -> 28736
    int*      labs    = (int*)  (ws + 28736);    // 8320 int  -> 62016
    unsigned char* G  = (unsigned char*)(ws + 62080);    // 8320*256 fp8 -> 2192000
    float*    pN      = (float*)(ws + 2192000);  // 65*8320 f32 -> 4355200

    hipMemsetAsync(ws, 0, 14400, stream);   // zero S_, CSacc, hist, lossacc, ticket

    kaccnorm<<<KACCB, 256, 0, stream>>>(feats, labels, S_, CSacc,
                                        (unsigned*)G, labs, hist);
    kproto<<<1, 256, 0, stream>>>(S_, CSacc, hist, protos, moms, G, CSfin, Pnorm);
    kmain<<<NBLK, 512, 0, stream>>>(G, labs, pN);
    kreduce<<<33, 256, 0, stream>>>(pN, feats, Pnorm, CSfin, hist, labs,
                                    lossacc, ticket, out);
}

// Round 11
// 110.434 us; speedup vs baseline: 1.3310x; 1.0052x over previous
//
#include <hip/hip_runtime.h>
#include <stdint.h>

// ---------------- problem constants ----------------
#define B    8192
#define D    256
#define C    7
#define NTOT 8199          // B + C
#define NPAD 8320          // 65 * 128 (padded rows)
#define NT   65            // 128-row tiles
#define NBLK 2145          // 65*66/2 triangular
#define BETAC 0.005f       // 0.5*(1-GAMMA)
#define L2GAMMA (-0.0144995696951151f)  // log2(0.99)
#define KC   (6.25f + 1.25e-7f)         // score offset
#define EC1  9.016844005555771f         // 6.25 * log2(e)
#define EC0  9.016844185925551f         // (6.25+1.25e-7) * log2(e)
#define KACCB 128                        // kaccnorm blocks (64 rows each)

using f32x4  = __attribute__((ext_vector_type(4))) float;

__device__ __forceinline__ void async16(const void* src, void* dst) {
    __builtin_amdgcn_global_load_lds(
        (const __attribute__((address_space(1))) void*)src,
        (__attribute__((address_space(3))) void*)dst, 16, 0, 0);
}

#define WAITVM(N) asm volatile("s_waitcnt vmcnt(" #N ")" ::: "memory")
#define BARRIER() do { __builtin_amdgcn_s_barrier(); asm volatile("" ::: "memory"); } while(0)

// ---------------- kernel 0: zero the 14.4 KB accumulator prefix ----------------
__global__ void kzero(float4* __restrict__ p) {
    int i = blockIdx.x * 256 + threadIdx.x;
    if (i < 900) p[i] = make_float4(0.f, 0.f, 0.f, 0.f);
}

// ---------------- kernel 1: fused scan+weights+normalize->fp8 G + atomic S/CS ----------------
__global__ void kaccnorm(const float* __restrict__ feats, const int* __restrict__ labels,
                         float* __restrict__ S, float* __restrict__ CSacc,
                         unsigned* __restrict__ G32, int* __restrict__ labs_ext,
                         int* __restrict__ hist) {
    __shared__ int cnt[256 * 8];
    __shared__ int tot[8];
    __shared__ float wrow[64];
    __shared__ float sacc[4][7][256];   // 28 KB reduction buffer (S then CS)
    int t = threadIdx.x, lane = t & 63, w = t >> 6;
    int bid = blockIdx.x;

    // ---- full-batch label scan (every block redundantly; deterministic) ----
    int lab[32];
    #pragma unroll
    for (int q = 0; q < 8; ++q) {
        int4 v = *(const int4*)(labels + t * 32 + q * 4);
        lab[q * 4 + 0] = v.x; lab[q * 4 + 1] = v.y;
        lab[q * 4 + 2] = v.z; lab[q * 4 + 3] = v.w;
    }
    int myc[8] = {0, 0, 0, 0, 0, 0, 0, 0};
    #pragma unroll
    for (int k = 0; k < 32; ++k) {
        #pragma unroll
        for (int cc = 0; cc < 7; ++cc) myc[cc] += (lab[k] == cc) ? 1 : 0;
    }
    #pragma unroll
    for (int cc = 0; cc < 8; ++cc) cnt[t * 8 + cc] = myc[cc];
    __syncthreads();
    for (int c = w; c < C; c += 4) {
        int v[4], partial = 0;
        #pragma unroll
        for (int k = 0; k < 4; ++k) { v[k] = cnt[(lane * 4 + k) * 8 + c]; partial += v[k]; }
        int inc = partial;
        #pragma unroll
        for (int d = 1; d < 64; d <<= 1) {
            int y = __shfl_up(inc, d);
            if (lane >= d) inc += y;
        }
        int run = inc - partial;
        #pragma unroll
        for (int k = 0; k < 4; ++k) { int tmp = v[k]; cnt[(lane * 4 + k) * 8 + c] = run; run += tmp; }
        if (lane == 63) { tot[c] = inc; if (bid == 0) hist[c] = inc; }
    }
    __syncthreads();
    // ---- weights for this block's 64 rows (chunks 2bid, 2bid+1) ----
    if (t < 2) {
        int ch = 2 * bid + t;
        int loc[7];
        #pragma unroll
        for (int cc = 0; cc < 7; ++cc) loc[cc] = cnt[ch * 8 + cc];
        for (int k = 0; k < 32; ++k) {
            int c2 = labels[ch * 32 + k];
            int r = ++loc[c2];
            wrow[t * 32 + k] = exp2f((float)(tot[c2] - r) * L2GAMMA);
        }
    }
    if (t < 64) labs_ext[bid * 64 + t] = labels[bid * 64 + t];
    if (bid == 0) {
        if (t < 128) { int i2 = B + t; labs_ext[i2] = (i2 < NTOT) ? (i2 - B) : -1; }
        // zero fp8 pad rows 8199..8319 (121 rows * 64 uints)
        for (int idx = t; idx < 121 * 64; idx += 256) G32[NTOT * 64 + idx] = 0u;
    }
    __syncthreads();

    // ---- main: normalize -> fp8, accumulate S (w*f) and CS (normalized g) ----
    float acc7[7][4] = {};
    float cs7[7][4] = {};
    int base = bid * 64 + w * 16;
    for (int k = 0; k < 16; ++k) {
        int row = base + k;
        const float4 v = *(const float4*)(feats + (size_t)row * 256 + lane * 4);
        float ss = v.x * v.x + v.y * v.y + v.z * v.z + v.w * v.w;
        #pragma unroll
        for (int off = 1; off < 64; off <<= 1) ss += __shfl_xor(ss, off);
        float rn = 1.f / sqrtf(ss);
        float g0 = v.x * rn, g1 = v.y * rn, g2 = v.z * rn, g3 = v.w * rn;
        unsigned p = (unsigned)__builtin_amdgcn_cvt_pk_fp8_f32(g0, g1, 0, false);
        p = (unsigned)__builtin_amdgcn_cvt_pk_fp8_f32(g2, g3, (int)p, true);
        G32[(size_t)row * 64 + lane] = p;
        int c = labels[row];               // wave-uniform
        float wgt = wrow[w * 16 + k];
        #pragma unroll
        for (int cc = 0; cc < 7; ++cc)
            if (c == cc) {
                acc7[cc][0] += wgt * v.x; acc7[cc][1] += wgt * v.y;
                acc7[cc][2] += wgt * v.z; acc7[cc][3] += wgt * v.w;
                cs7[cc][0] += g0; cs7[cc][1] += g1;
                cs7[cc][2] += g2; cs7[cc][3] += g3;
            }
    }
    #pragma unroll
    for (int cc = 0; cc < 7; ++cc)
        #pragma unroll
        for (int jj = 0; jj < 4; ++jj) sacc[w][cc][lane * 4 + jj] = acc7[cc][jj];
    __syncthreads();
    #pragma unroll
    for (int cc = 0; cc < 7; ++cc) {
        float s = sacc[0][cc][t] + sacc[1][cc][t] + sacc[2][cc][t] + sacc[3][cc][t];
        atomicAdd(&S[cc * 256 + t], s);
    }
    __syncthreads();
    #pragma unroll
    for (int cc = 0; cc < 7; ++cc)
        #pragma unroll
        for (int jj = 0; jj < 4; ++jj) sacc[w][cc][lane * 4 + jj] = cs7[cc][jj];
    __syncthreads();
    #pragma unroll
    for (int cc = 0; cc < 7; ++cc) {
        float s = sacc[0][cc][t] + sacc[1][cc][t] + sacc[2][cc][t] + sacc[3][cc][t];
        atomicAdd(&CSacc[cc * 256 + t], s);
    }
}

// ---------------- kernel 2: target + Householder QR + proto rows + CSfin ----------------
__global__ void kproto(const float* __restrict__ S, const float* __restrict__ CSacc,
                       const int* __restrict__ hist, const float* __restrict__ protos,
                       const float* __restrict__ moms, unsigned char* __restrict__ G8,
                       float* __restrict__ CSfin, float* __restrict__ Pnorm) {
    __shared__ float A[256 * 8];
    __shared__ float V[256 * 8];
    __shared__ float vvs[8];
    __shared__ float bcast[8];
    int t = threadIdx.x;
    int lane = t & 63, w = t >> 6;
    float cssum[7];
    #pragma unroll
    for (int cc = 0; cc < 7; ++cc) cssum[cc] = CSacc[cc * 256 + t];
    #pragma unroll
    for (int c = 0; c < C; ++c) {
        float p = protos[c * 256 + t];
        float m0 = moms[c * 256 + t];
        float gn = exp2f((float)hist[c] * L2GAMMA);     // gamma^{n_c}
        float mf = gn * m0 + BETAC * S[c * 256 + t] - 0.5f * (1.f - gn) * p;
        A[t * 8 + c] = p + mf;
        V[t * 8 + c] = 0.f;
    }
    __syncthreads();
    for (int j = 0; j < C; ++j) {
        if (w == 0) {
            float s = 0.f;
            for (int i = lane; i < 256; i += 64) {
                float a = (i >= j) ? A[i * 8 + j] : 0.f;
                s += a * a;
            }
            #pragma unroll
            for (int off = 32; off; off >>= 1) s += __shfl_xor(s, off);
            if (lane == 0) {
                float norm = sqrtf(s);
                float alpha = A[j * 8 + j];
                float beta = (alpha >= 0.f) ? -norm : norm;
                float vv = 2.f * beta * (beta - alpha);
                bcast[0] = alpha; bcast[1] = beta;
                bcast[2] = (vv > 0.f) ? 1.f : 0.f;
                vvs[j] = (vv > 0.f) ? vv : 1.f;
            }
        }
        __syncthreads();
        float alpha = bcast[0], valid = bcast[2];
        float beta = bcast[1];
        float vi = 0.f;
        if (valid != 0.f) {
            if (t == j) vi = alpha - beta;
            else if (t > j) vi = A[t * 8 + j];
        }
        V[t * 8 + j] = vi;
        __syncthreads();
        float vvj = vvs[j];
        for (int k = j + 1 + w; k < C; k += 4) {
            float cp = 0.f;
            for (int i = lane; i < 256; i += 64) cp += V[i * 8 + j] * A[i * 8 + k];
            #pragma unroll
            for (int off = 32; off; off >>= 1) cp += __shfl_xor(cp, off);
            float scale = 2.f * cp / vvj;
            for (int i = lane; i < 256; i += 64) A[i * 8 + k] -= scale * V[i * 8 + j];
        }
        __syncthreads();
    }
    #pragma unroll
    for (int c = 0; c < C; ++c) A[t * 8 + c] = (t == c) ? 1.f : 0.f;
    __syncthreads();
    for (int j = C - 1; j >= 0; --j) {
        float vvj = vvs[j];
        for (int k = w; k < C; k += 4) {
            float cp = 0.f;
            for (int i = lane; i < 256; i += 64) cp += V[i * 8 + j] * A[i * 8 + k];
            #pragma unroll
            for (int off = 32; off; off >>= 1) cp += __shfl_xor(cp, off);
            float scale = 2.f * cp / vvj;
            for (int i = lane; i < 256; i += 64) A[i * 8 + k] -= scale * V[i * 8 + j];
        }
        __syncthreads();
    }
    for (int c = w; c < C; c += 4) {
        float s = 0.f;
        for (int i = lane; i < 256; i += 64) { float a = A[i * 8 + c]; s += a * a; }
        #pragma unroll
        for (int off = 32; off; off >>= 1) s += __shfl_xor(s, off);
        if (lane == 0) bcast[c] = 1.f / sqrtf(s);
    }
    __syncthreads();
    #pragma unroll
    for (int c = 0; c < C; ++c) {
        float val = A[t * 8 + c] * bcast[c];
        int pk = __builtin_amdgcn_cvt_pk_fp8_f32(val, 0.f, 0, false);
        G8[(size_t)(B + c) * 256 + t] = (unsigned char)(pk & 0xff);
        Pnorm[c * 256 + t] = val;
        CSfin[c * 256 + t] = cssum[c] + val;   // class sums incl. prototype row
    }
}

// ---------------- kernel 3: 128x128 symmetric fused G G^T, neg-only epilogue ----------------
__global__ __launch_bounds__(512, 2) void kmain(const unsigned char* __restrict__ G,
                                                const int* __restrict__ labs,
                                                float* __restrict__ pN) {
    __shared__ unsigned char Asm_[128 * 256];   // full-K fp8 A tile (32 KB)
    __shared__ unsigned char Bsm_[128 * 256];   // full-K fp8 B tile (32 KB)
    // epilogue overlays into Asm_ (after a barrier): 6 x [128] floats
    float* rowN = (float*)Asm_;                 // [2][128]
    float* colN = rowN + 256;                   // [4][128]

    // bijective XCD swizzle: NBLK = 2145 = 8*268 + 1 (residue 0 gets 269)
    int b0 = blockIdx.x;
    int xcd = b0 & 7, pos = b0 >> 3;
    int b = (xcd == 0) ? pos : (269 + (xcd - 1) * 268 + pos);

    // triangular decode: pairs (it <= jt)
    int jt = (int)((sqrtf(8.f * (float)b + 1.f) - 1.f) * 0.5f);
    while ((jt * (jt + 1)) / 2 > b) --jt;
    while (((jt + 1) * (jt + 2)) / 2 <= b) ++jt;
    int it = b - (jt * (jt + 1)) / 2;

    int rowA = it * 128, rowB = jt * 128;
    int tid = threadIdx.x, lane = tid & 63, w8 = tid >> 6;
    int wr = w8 >> 1, wc = w8 & 1;              // 4x2 wave grid: 32 rows x 64 cols per wave
    int g4 = lane >> 4, q15 = lane & 15;

    const char* gb = (const char*)G;

    // ---- single-shot staging: 8 loads/thread in flight, one wait.
    #pragma unroll
    for (int q = 0; q < 4; ++q) {
        int o = q * 8192 + tid * 16;
        int row = o >> 8, colb = o & 255;
        int sc = colb ^ ((row & 15) << 4);
        async16(gb + (size_t)(rowA + row) * 256 + sc, (char*)Asm_ + o);
    }
    #pragma unroll
    for (int q = 0; q < 4; ++q) {
        int o = q * 8192 + tid * 16;
        int row = o >> 8, colb = o & 255;
        int sc = colb ^ ((row & 15) << 4);
        async16(gb + (size_t)(rowB + row) * 256 + sc, (char*)Bsm_ + o);
    }

    // label prefetch into registers — overlaps the stage latency
    int ljv[4];
    #pragma unroll
    for (int n = 0; n < 4; ++n) ljv[n] = labs[rowB + wc * 64 + n * 16 + q15];
    int4 lrow[2];
    #pragma unroll
    for (int m = 0; m < 2; ++m)
        lrow[m] = *(const int4*)(labs + rowA + wr * 32 + m * 16 + g4 * 4);

    f32x4 acc[2][4];
    #pragma unroll
    for (int m = 0; m < 2; ++m)
        #pragma unroll
        for (int n = 0; n < 4; ++n) acc[m][n] = 0.f;

    WAITVM(0);
    BARRIER();

    // ---- mega K-step: 64 MFMA per wave, no barriers
    #pragma unroll
    for (int kk = 0; kk < 8; ++kk) {
        long af[2], bfr[4];
        int cb = (kk * 32 + g4 * 8) ^ (q15 << 4);
        #pragma unroll
        for (int m = 0; m < 2; ++m) {
            int r0 = wr * 32 + m * 16 + q15;
            af[m] = *(const long*)((const char*)Asm_ + r0 * 256 + cb);
        }
        #pragma unroll
        for (int n = 0; n < 4; ++n) {
            int r0 = wc * 64 + n * 16 + q15;
            bfr[n] = *(const long*)((const char*)Bsm_ + r0 * 256 + cb);
        }
        __builtin_amdgcn_s_setprio(1);
        #pragma unroll
        for (int m = 0; m < 2; ++m)
            #pragma unroll
            for (int n = 0; n < 4; ++n)
                acc[m][n] = __builtin_amdgcn_mfma_f32_16x16x32_fp8_fp8(af[m], bfr[n], acc[m][n], 0, 0, 0);
        __builtin_amdgcn_s_setprio(0);
    }

    __syncthreads();   // all LDS reads done before epilogue overlay writes

    // ---- neg-only epilogue: e = exp(score) = exp2(fma(sim, EC1, EC0))
    float cn[4] = {0.f, 0.f, 0.f, 0.f};
    bool fastpath = (it != jt) && (jt != NT - 1);

#define EPI(VALIDEXPR)                                                         \
    _Pragma("unroll")                                                          \
    for (int m = 0; m < 2; ++m) {                                              \
        _Pragma("unroll")                                                      \
        for (int r = 0; r < 4; ++r) {                                          \
            int il = wr * 32 + m * 16 + g4 * 4 + r;                            \
            int i = rowA + il; (void)i;                                        \
            int li = ((const int*)&lrow[m])[r];                                \
            float ns = 0.f;                                                    \
            _Pragma("unroll")                                                  \
            for (int n = 0; n < 4; ++n) {                                      \
                int j = rowB + wc * 64 + n * 16 + q15; (void)j;                \
                float sim = acc[m][n][r];                                      \
                float e = exp2f(fmaf(sim, EC1, EC0));                          \
                bool keep = (VALIDEXPR) && (li != ljv[n]);                     \
                float me = keep ? e : 0.f;                                     \
                ns += me; cn[n] += me;                                         \
            }                                                                  \
            _Pragma("unroll")                                                  \
            for (int off = 1; off < 16; off <<= 1) ns += __shfl_xor(ns, off);  \
            if (q15 == 0) rowN[wc * 128 + il] = ns;                            \
        }                                                                      \
    }

    if (fastpath) { EPI(true); }
    else          { EPI(i < NTOT && j < NTOT && i != j); }
#undef EPI

    // col-side: reduce over g4 groups (same q15-column, different rows)
    #pragma unroll
    for (int n = 0; n < 4; ++n) {
        float a = cn[n];
        a += __shfl_xor(a, 16); a += __shfl_xor(a, 32);
        if (g4 == 0) colN[wr * 128 + wc * 64 + n * 16 + q15] = a;
    }

    __syncthreads();
    if (tid < 128) {
        pN[(size_t)jt * NPAD + rowA + tid] = rowN[tid] + rowN[128 + tid];
    } else if (tid < 256 && it != jt) {
        int tt = tid - 128;
        pN[(size_t)it * NPAD + rowB + tt] = colN[tt] + colN[128 + tt] + colN[256 + tt] + colN[384 + tt];
    }
}

// ---------------- kernel 4: neg reduce + closed-form pos + masked-mean finalize ----------------
__global__ void kreduce(const float* __restrict__ pN, const float* __restrict__ feats,
                        const float* __restrict__ Pnorm, const float* __restrict__ CSfin,
                        const int* __restrict__ hist, const int* __restrict__ labs,
                        float* __restrict__ lossacc, unsigned* __restrict__ ticket,
                        float* __restrict__ out) {
    __shared__ float cls[7 * 264];   // padded class-sum vectors (bank-spread)
    int tid = threadIdx.x;
    for (int idx = tid; idx < 7 * 256; idx += 256)
        cls[(idx >> 8) * 264 + (idx & 255)] = CSfin[idx];
    __syncthreads();

    int i = blockIdx.x * 256 + tid;
    float lsum = 0.f, lcnt = 0.f;
    if (i < NTOT) {
        float sn = 0.f;
        #pragma unroll 5
        for (int c = 0; c < NT; ++c) sn += pN[(size_t)c * NPAD + i];

        int c = labs[i];
        const float* cv = cls + c * 264;
        float dot = 0.f;
        if (i < B) {
            float ss = 0.f;
            const float* fr = feats + (size_t)i * 256;
            for (int k4 = 0; k4 < 64; ++k4) {
                float4 v = *(const float4*)(fr + k4 * 4);
                float4 cvv = *(const float4*)(cv + k4 * 4);
                ss += v.x * v.x + v.y * v.y + v.z * v.z + v.w * v.w;
                dot += v.x * cvv.x + v.y * cvv.y + v.z * cvv.z + v.w * cvv.w;
            }
            dot *= 1.f / sqrtf(ss);
        } else {
            const float* pr = Pnorm + (size_t)(i - B) * 256;
            for (int k4 = 0; k4 < 64; ++k4) {
                float4 v = *(const float4*)(pr + k4 * 4);
                float4 cvv = *(const float4*)(cv + k4 * 4);
                dot += v.x * cvv.x + v.y * cvv.y + v.z * cvv.z + v.w * cvv.w;
            }
        }
        float cnt = (float)hist[c];
        // pos = (sum of same-class scores excl. self) / (cnt + eps); M=0 shift
        float pos = (6.25f * (dot - 1.f) + cnt * KC) / (cnt + 1e-8f);
        float neg = logf(sn + 1e-8f);
        float loss = neg - pos;
        if (loss > 0.f) { lsum = loss; lcnt = 1.f; }
    }
    #pragma unroll
    for (int off = 1; off < 64; off <<= 1) {
        lsum += __shfl_xor(lsum, off);
        lcnt += __shfl_xor(lcnt, off);
    }
    __shared__ float s1[4], s2[4];
    int lane = tid & 63, w = tid >> 6;
    if (lane == 0) { s1[w] = lsum; s2[w] = lcnt; }
    __syncthreads();
    if (tid == 0) {
        atomicAdd(&lossacc[0], s1[0] + s1[1] + s1[2] + s1[3]);
        atomicAdd(&lossacc[1], s2[0] + s2[1] + s2[2] + s2[3]);
        __threadfence();
        unsigned tk = atomicAdd(ticket, 1u);
        if (tk == 32) {   // last of 33 blocks
            float a = atomicAdd(&lossacc[0], 0.f);
            float c2 = atomicAdd(&lossacc[1], 0.f);
            out[0] = (c2 > 0.f) ? a / fmaxf(c2, 1.f) : 0.f;
        }
    }
}

// ---------------- launcher ----------------
extern "C" void kernel_launch(void* const* d_in, const int* in_sizes, int n_in,
                              void* d_out, int out_size, void* d_ws, size_t ws_size,
                              hipStream_t stream) {
    const float* feats  = (const float*)d_in[0];
    const int*   labels = (const int*)d_in[1];
    const float* protos = (const float*)d_in[2];
    const float* moms   = (const float*)d_in[3];
    float* out = (float*)d_out;

    char* ws = (char*)d_ws;
    float*    S_      = (float*)(ws + 0);        // 1792 f32  -> 7168
    float*    CSacc   = (float*)(ws + 7168);     // 1792 f32  -> 14336
    int*      hist    = (int*)  (ws + 14336);    // 8 int     -> 14368
    float*    lossacc = (float*)(ws + 14368);    // 2 f32     -> 14376
    unsigned* ticket  = (unsigned*)(ws + 14376); // 1 u32     -> 14380
    float*    CSfin   = (float*)(ws + 14400);    // 1792 f32  -> 21568
    float*    Pnorm   = (float*)(ws + 21568);    // 1792 f32  -> 28736
    int*      labs    = (int*)  (ws + 28736);    // 8320 int  -> 62016
    unsigned char* G  = (unsigned char*)(ws + 62080);    // 8320*256 fp8 -> 2192000
    float*    pN      = (float*)(ws + 2192000);  // 65*8320 f32 -> 4355200

    kzero<<<4, 256, 0, stream>>>((float4*)ws);   // zero S_, CSacc, hist, lossacc, ticket
    kaccnorm<<<KACCB, 256, 0, stream>>>(feats, labels, S_, CSacc,
                                        (unsigned*)G, labs, hist);
    kproto<<<1, 256, 0, stream>>>(S_, CSacc, hist, protos, moms, G, CSfin, Pnorm);
    kmain<<<NBLK, 512, 0, stream>>>(G, labs, pN);
    kreduce<<<33, 256, 0, stream>>>(pN, feats, Pnorm, CSfin, hist, labs,
                                    lossacc, ticket, out);
}